// Round 16
// baseline (127.890 us; speedup 1.0000x reference)
//
#include <hip/hip_runtime.h>
#include <math.h>

#define BB 8
#define CC 128
#define HH 64
#define WW 64
#define NPTS 9
#define OUTC 256
#define HW (HH*WW)
#define KTOT (CC*NPTS)    // 1152 original K
#define NCHUNK 8          // 16-channel chunks
#define BKP 160           // padded K per chunk (144 real + 16 zero)
#define KP (NCHUNK*BKP)   // 1280 padded K total
#define APW 81            // Atile row stride in words (odd -> bank spread)
#define WROWS 6           // x row window: global rows h-2 .. h+3

typedef __attribute__((ext_vector_type(8))) short bf16x8;
typedef __attribute__((ext_vector_type(4))) float f32x4;

// bf16 weights, padded-permuted k: k = chunk*160 + pair*18 + n*2 + half
// (k%160 >= 144 -> zero), channel c = chunk*16 + pair*2 + half.
__device__ unsigned short g_wT[OUTC * KP];     // 655 KB
__device__ unsigned short g_woT[32 * KP];      // 82 KB
__device__ float g_part[512 * 2 * 27 * 64];    // 7.08 MB offset-conv partials

__device__ __forceinline__ unsigned short f2bf(float f) {
    unsigned int u = __builtin_bit_cast(unsigned int, f);
    unsigned int r = (u + 0x7FFFu + ((u >> 16) & 1u)) >> 16;   // RNE
    return (unsigned short)r;
}
__device__ __forceinline__ unsigned cvtpk(float lo, float hi) {
    unsigned r;
    asm("v_cvt_pk_bf16_f32 %0, %1, %2" : "=v"(r) : "v"(lo), "v"(hi));
    return r;
}
__device__ __forceinline__ float bflo(unsigned w) { return __builtin_bit_cast(float, w << 16); }
__device__ __forceinline__ float bfhi(unsigned w) { return __builtin_bit_cast(float, w & 0xFFFF0000u); }

__device__ __forceinline__ int orig_k(int k) {   // padded-permuted -> c*9+n, or -1
    int chunk = k / BKP, r = k % BKP;
    if (r >= 144) return -1;
    int pair = r / 18, r2 = r % 18;
    int n = r2 >> 1, half = r2 & 1;
    return (chunk * 16 + pair * 2 + half) * NPTS + n;
}

__global__ __launch_bounds__(256) void prep_kernel(
    const float* __restrict__ wo, const float* __restrict__ wm,
    const float* __restrict__ wc)
{
    int idx = blockIdx.x * 256 + threadIdx.x;
    const int T1 = 32 * KP;
    if (idx < T1) {
        int nn = idx / KP, k = idx - nn * KP;
        int ok = orig_k(k);
        float v = 0.f;
        if (ok >= 0) {
            if (nn < 18)      v = wo[nn * KTOT + ok];
            else if (nn < 27) v = wm[(nn - 18) * KTOT + ok];
        }
        g_woT[idx] = f2bf(v);
    } else if (idx < T1 + OUTC * KP) {
        int j = idx - T1;
        int oc = j / KP, k = j - oc * KP;
        int ok = orig_k(k);
        g_wT[j] = f2bf(ok >= 0 ? wc[oc * KTOT + ok] : 0.f);
    }
}

// Pair staging: wave w stages AND consumes pair w (channels chunk*16+2w,+1)
// -> window wave-private, no barriers around commit/build. PF = 6 VGPRs.
struct PF { unsigned w[WROWS]; };

__device__ __forceinline__ void issue(PF& pf, const float* __restrict__ xb,
                                      int h, int chunk, int wv, int lane) {
    const float* base = xb + (size_t)(chunk * 16 + 2 * wv) * HW + lane;
    #pragma unroll
    for (int r = 0; r < WROWS; ++r) {
        int gr = h - 2 + r;
        bool v = (gr >= 0) & (gr < HH);
        float a0 = v ? base[gr * WW] : 0.f;
        float a1 = v ? base[HW + gr * WW] : 0.f;
        pf.w[r] = cvtpk(a0, a1);
    }
}
__device__ __forceinline__ void commit(unsigned* win, const PF& pf, int wv, int lane) {
    unsigned* wp = win + wv * 384 + lane;
    #pragma unroll
    for (int r = 0; r < WROWS; ++r) wp[r * 64] = pf.w[r];
}

// ===== k1: offset/mask conv partials. grid 1024 = (b, h, K-half). =========
// LDS 33 KB -> 4 blocks/CU, 32 waves/CU (8/SIMD). VGPR demand ~45 < 64.
__global__ __launch_bounds__(512) __attribute__((amdgpu_waves_per_eu(8, 8)))
void offconv_kernel(const float* __restrict__ x)
{
    __shared__ unsigned short Atile[64][2 * APW];   // 20736 B (81 words/row)
    __shared__ unsigned win[8 * 384];               // 12288 B pair-packed bf16

    int bid = blockIdx.x;
    int b = bid & 7;                    // one batch per XCD (L2 locality)
    int local = bid >> 3;
    int h = local >> 1, kh = local & 1; // kh: chunks 0-3 or 4-7
    int tid  = threadIdx.x;
    int lane = tid & 63;
    int wv   = __builtin_amdgcn_readfirstlane(tid >> 6);
    int l15  = lane & 15;
    int kg   = lane >> 4;

    const float* xb = x + (size_t)b * CC * HW;
    unsigned* AtU = (unsigned*)&Atile[0][0];

    // zero K-pad words 72..79 once (never written by builds)
    AtU[(tid & 63) * APW + 72 + (tid >> 6)] = 0u;

    int mi_a = wv & 3, nf_a = wv >> 2;
    f32x4 s1acc = {0.f, 0.f, 0.f, 0.f};

    PF pf; issue(pf, xb, h, kh * 4, wv, lane);
    for (int i = 0; i < 4; ++i) {
        int c = kh * 4 + i;
        commit(win, pf, wv, lane);      // wave-private
        {   // build 3x3 patch for this wave's pair
            const unsigned* basep = win + wv * 384;
            #pragma unroll
            for (int tap = 0; tap < 9; ++tap) {
                int ky = tap / 3, kx = tap % 3;
                int col  = lane + kx - 1;
                int colc = min(max(col, 0), WW - 1);
                unsigned w = basep[(ky + 1) * 64 + colc];
                w = (col >= 0 && col < WW) ? w : 0u;
                AtU[lane * APW + wv * 9 + tap] = w;
            }
        }
        if (i < 3) issue(pf, xb, h, c + 1, wv, lane);
        __syncthreads();                // Atile complete (covers pad-zero too)
        __builtin_amdgcn_s_setprio(1);
        for (int q = 0; q < 5; ++q) {
            int koff = q * 32 + kg * 8;
            bf16x8 af = *(const bf16x8*)&Atile[mi_a * 16 + l15][koff];
            int nn = nf_a * 16 + l15;
            bf16x8 bfr = *(const bf16x8*)&g_woT[nn * KP + c * BKP + koff];
            s1acc = __builtin_amdgcn_mfma_f32_16x16x32_bf16(af, bfr, s1acc, 0, 0, 0);
        }
        __builtin_amdgcn_s_setprio(0);
        __syncthreads();
    }

    // write partials: g_part[(blk*2+kh)][nn][pixl]
    int blk = b * 64 + h;
    int nn = nf_a * 16 + l15;
    if (nn < 27) {
        #pragma unroll
        for (int j = 0; j < 4; ++j) {
            int pixl = mi_a * 16 + kg * 4 + j;
            g_part[((size_t)(blk * 2 + kh) * 27 + nn) * 64 + pixl] = s1acc[j];
        }
    }
}

// ===== k2: params + bilinear + main GEMM. grid 1024 = (b, h, octile). =====
// LDS 46.8 KB -> 3 blocks/CU. Each wave owns 16 ocs (acc[4] = 16 VGPRs).
__global__ __launch_bounds__(512) __attribute__((amdgpu_waves_per_eu(4, 8)))
void main_kernel(
    const float* __restrict__ x,
    const float* __restrict__ b_offset, const float* __restrict__ b_mask,
    const float* __restrict__ bn_gamma, const float* __restrict__ bn_beta,
    const float* __restrict__ bn_mean,  const float* __restrict__ bn_var,
    float* __restrict__ out)
{
    __shared__ unsigned short Atile[64][2 * APW];   // 20736 B
    __shared__ unsigned win[8 * 384];               // 12288 B
    __shared__ float4 gtab[NPTS][64];               //  9216 B
    __shared__ uint2  otab[NPTS][64];               //  4608 B

    int bid = blockIdx.x;
    int b = bid & 7;
    int local = bid >> 3;
    int h = local >> 1, oct = local & 1;
    int tid  = threadIdx.x;
    int lane = tid & 63;
    int wv   = __builtin_amdgcn_readfirstlane(tid >> 6);
    int l15  = lane & 15;
    int kg   = lane >> 4;

    const float* xb = x + (size_t)b * CC * HW;
    unsigned* AtU = (unsigned*)&Atile[0][0];
    int blk = b * 64 + h;

    AtU[(tid & 63) * APW + 72 + (tid >> 6)] = 0u;   // zero K-pad words

    // ---- params from k1 partials (both octile blocks recompute: cheap) ----
    if (tid < 64) {
        int t = tid;
        const float* p0 = &g_part[(size_t)(blk * 2 + 0) * 27 * 64];
        const float* p1 = &g_part[(size_t)(blk * 2 + 1) * 27 * 64];
        #pragma unroll
        for (int n = 0; n < NPTS; ++n) {
            float px = p0[n * 64 + t] + p1[n * 64 + t]
                     + b_offset[n] + (float)(n / 3 - 1) + (float)(h + 1);
            float py = p0[(9 + n) * 64 + t] + p1[(9 + n) * 64 + t]
                     + b_offset[9 + n] + (float)(n % 3 - 1) + (float)(t + 1);
            float sg = p0[(18 + n) * 64 + t] + p1[(18 + n) * 64 + t] + b_mask[n];
            float m  = 1.f / (1.f + expf(-sg));
            float fx = floorf(px), fy = floorf(py);
            float qltx = fminf(fmaxf(fx,       0.f), 65.f);
            float qlty = fminf(fmaxf(fy,       0.f), 65.f);
            float qrbx = fminf(fmaxf(fx + 1.f, 0.f), 65.f);
            float qrby = fminf(fmaxf(fy + 1.f, 0.f), 65.f);
            float pxc  = fminf(fmaxf(px, 0.f), 65.f);
            float pyc  = fminf(fmaxf(py, 0.f), 65.f);
            float glt = (1.f + (qltx - pxc)) * (1.f + (qlty - pyc)) * m;
            float grb = (1.f - (qrbx - pxc)) * (1.f - (qrby - pyc)) * m;
            float glb = (1.f + (qltx - pxc)) * (1.f - (qrby - pyc)) * m;
            float grt = (1.f - (qrbx - pxc)) * (1.f + (qlty - pyc)) * m;
            int i0 = (int)qltx - 1, j0 = (int)qlty - 1;
            int i1 = (int)qrbx - 1, j1 = (int)qrby - 1;
            bool v00 = (i0 >= 0) & (i0 < HH) & (j0 >= 0) & (j0 < WW);
            bool v11 = (i1 >= 0) & (i1 < HH) & (j1 >= 0) & (j1 < WW);
            bool v01 = (i0 >= 0) & (i0 < HH) & (j1 >= 0) & (j1 < WW);
            bool v10 = (i1 >= 0) & (i1 < HH) & (j0 >= 0) & (j0 < WW);
            float4 g;
            g.x = v00 ? glt : 0.f;
            g.y = v11 ? grb : 0.f;
            g.z = v01 ? glb : 0.f;
            g.w = v10 ? grt : 0.f;
            gtab[n][t] = g;
            bool okr0 = ((i0 >= h - 2) & (i0 <= h + 3)) | !(v00 | v01);
            bool okr1 = ((i1 >= h - 2) & (i1 <= h + 3)) | !(v11 | v10);
            bool ok = okr0 & okr1;
            int r0w = min(max(i0 - (h - 2), 0), WROWS - 1);
            int r1w = min(max(i1 - (h - 2), 0), WROWS - 1);
            int r0g = min(max(i0, 0), HH - 1);
            int r1g = min(max(i1, 0), HH - 1);
            int j0c = min(max(j0, 0), WW - 1);
            int j1c = min(max(j1, 0), WW - 1);
            int o  = ok ? (r0w * WW + j0c) : (r0g * WW + j0c);
            int dr = ok ? (r1w - r0w) : (r1g - r0g);
            int dj = j1c - j0c;
            unsigned o00 = (unsigned)o;
            unsigned o11 = (unsigned)(o + dr * WW + dj);
            unsigned o01 = (unsigned)(o + dj);
            unsigned o10 = (unsigned)(o + dr * WW);
            uint2 ot;
            ot.x = (o00 | (ok ? 0u : 0x8000u)) | (o11 << 16);
            ot.y = o01 | (o10 << 16);
            otab[n][t] = ot;
        }
    }
    __syncthreads();

    // ---- main GEMM: M=64 pixels x N=128 ocs (this octile) x K=1280 -------
    f32x4 acc[4];
    #pragma unroll
    for (int mi = 0; mi < 4; ++mi) acc[mi] = (f32x4){0.f, 0.f, 0.f, 0.f};
    int oc0 = oct * 128 + wv * 16;

    PF pf; issue(pf, xb, h, 0, wv, lane);
    for (int c = 0; c < NCHUNK; ++c) {
        commit(win, pf, wv, lane);          // wave-private window (pair c*16+2wv)
        {
            const unsigned* basep = win + wv * 384;
            const float* xgA = xb + (size_t)(c * 16 + 2 * wv) * HW;
            const float* xgB = xgA + HW;
            #pragma unroll
            for (int n = 0; n < NPTS; ++n) {
                float4 g  = gtab[n][lane];
                uint2  ot = otab[n][lane];
                int o00 = ot.x & 0x7FFF;
                int o11 = ot.x >> 16;
                int o01 = ot.y & 0xFFFF;
                int o10 = ot.y >> 16;
                float v0, v1;
                if (!(ot.x & 0x8000u)) {    // in-window pair-packed reads
                    unsigned w00 = basep[o00];
                    unsigned w11 = basep[o11];
                    unsigned w01 = basep[o01];
                    unsigned w10 = basep[o10];
                    v0 =       g.x * bflo(w00);
                    v0 = fmaf(g.y, bflo(w11), v0);
                    v0 = fmaf(g.z, bflo(w01), v0);
                    v0 = fmaf(g.w, bflo(w10), v0);
                    v1 =       g.x * bfhi(w00);
                    v1 = fmaf(g.y, bfhi(w11), v1);
                    v1 = fmaf(g.z, bfhi(w01), v1);
                    v1 = fmaf(g.w, bfhi(w10), v1);
                } else {                    // rare: f32 global corners
                    v0 =       g.x * xgA[o00];
                    v0 = fmaf(g.y, xgA[o11], v0);
                    v0 = fmaf(g.z, xgA[o01], v0);
                    v0 = fmaf(g.w, xgA[o10], v0);
                    v1 =       g.x * xgB[o00];
                    v1 = fmaf(g.y, xgB[o11], v1);
                    v1 = fmaf(g.z, xgB[o01], v1);
                    v1 = fmaf(g.w, xgB[o10], v1);
                }
                AtU[lane * APW + wv * 9 + n] = cvtpk(v0, v1);
            }
        }
        if (c < NCHUNK - 1) issue(pf, xb, h, c + 1, wv, lane);
        __syncthreads();                    // Atile complete
        __builtin_amdgcn_s_setprio(1);
        for (int q = 0; q < 5; ++q) {
            int koff = q * 32 + kg * 8;
            bf16x8 af[4];
            #pragma unroll
            for (int mi = 0; mi < 4; ++mi)
                af[mi] = *(const bf16x8*)&Atile[mi * 16 + l15][koff];
            int oc = oc0 + l15;
            bf16x8 bfr = *(const bf16x8*)&g_wT[(size_t)oc * KP + c * BKP + koff];
            #pragma unroll
            for (int mi = 0; mi < 4; ++mi)
                acc[mi] = __builtin_amdgcn_mfma_f32_16x16x32_bf16(af[mi], bfr, acc[mi], 0, 0, 0);
        }
        __builtin_amdgcn_s_setprio(0);
        __syncthreads();                    // MFMA done; next build may overwrite
    }

    // ---- epilogue: BN + ReLU, float4 stores -------------------------------
    {
        int oc = oc0 + l15;
        float inv   = 1.f / sqrtf(bn_var[oc] + 1e-5f);
        float scale = bn_gamma[oc] * inv;
        float shift = bn_beta[oc] - bn_mean[oc] * scale;
        float* op = out + ((size_t)b * OUTC + oc) * HW + h * WW + kg * 4;
        #pragma unroll
        for (int mi = 0; mi < 4; ++mi) {
            f32x4 o4;
            #pragma unroll
            for (int j = 0; j < 4; ++j) {
                float v = fmaf(acc[mi][j], scale, shift);
                o4[j] = v > 0.f ? v : 0.f;
            }
            *(f32x4*)(op + mi * 16) = o4;
        }
    }
}

extern "C" void kernel_launch(void* const* d_in, const int* in_sizes, int n_in,
                              void* d_out, int out_size, void* d_ws, size_t ws_size,
                              hipStream_t stream) {
    (void)in_sizes; (void)n_in; (void)out_size; (void)d_ws; (void)ws_size;
    const float* x        = (const float*)d_in[0];
    const float* w_offset = (const float*)d_in[1];
    const float* b_offset = (const float*)d_in[2];
    const float* w_mask   = (const float*)d_in[3];
    const float* b_mask   = (const float*)d_in[4];
    const float* w_conv   = (const float*)d_in[5];
    const float* bn_gamma = (const float*)d_in[6];
    const float* bn_beta  = (const float*)d_in[7];
    const float* bn_mean  = (const float*)d_in[8];
    const float* bn_var   = (const float*)d_in[9];
    float* out = (float*)d_out;

    int prep_elems = 32 * KP + OUTC * KP;
    prep_kernel<<<(prep_elems + 255) / 256, 256, 0, stream>>>(w_offset, w_mask, w_conv);
    offconv_kernel<<<1024, 512, 0, stream>>>(x);
    main_kernel<<<1024, 512, 0, stream>>>(x, b_offset, b_mask,
                                          bn_gamma, bn_beta, bn_mean, bn_var, out);
}